// Round 16
// baseline (131.852 us; speedup 1.0000x reference)
//
#include <hip/hip_runtime.h>
#include <math.h>

// ---------------------------------------------------------------------------
// ScatteringNetwork — fused, rank-2 composed conv + theta-symmetry.
// R16: split into LEAN kernels (k_img / k_pairk) with no runtime path
// branches so hipcc's unroller actually fires (R12-R15 all reported
// VGPR=48-52 -> rolled loops -> dependent-FMA latency bound). g0/g5 run as
// degenerate pairs (ga==gb): ~8% redundant FMA, one uniform code path.
// C phase: i-outer, 12 named accumulator chains.
//
// ws: [0) pimg 8*288*288 (border 16, zero) ; [663552) fhp 10*136
// fhp per ch: [0)H'r [17)H'i [34)H''r [51)H''i [68)F'r [85)F'i [102)F''r [119)F''i
// ---------------------------------------------------------------------------

#define PIMG_SZ (288 * 288)
#define FHP_OFF (8 * PIMG_SZ)
#define SSTR  284            // strip row stride (27 rows)
#define W1    298            // s1 swizzled row stride (tsw 0..297)
#define S1SZ  (17 * 298)
#define IVSTR 300
#define IVPL  (17 * 300)
#define CSTR  600            // C per-plane stride (re@0, im@300)

// ---------------- k_prep: padded img copy + factor table (proven) ----------
__global__ __launch_bounds__(256) void k_prep(const float* __restrict__ img,
                                              const float* __restrict__ psi_re,
                                              const float* __restrict__ psi_im,
                                              const float* __restrict__ blur,
                                              float* __restrict__ pimg,
                                              float* __restrict__ fhp) {
    int bid = blockIdx.x, tid = threadIdx.x;
    if (bid < 288) {
        int n = bid / 36, rg = bid - n * 36;
        float* dst = pimg + n * PIMG_SZ + rg * 8 * 288;
        const float* src = img + n * 65536;
        for (int i = tid; i < 576; i += 256) {
            int lr = i / 72, c4 = i - lr * 72;
            int prow = rg * 8 + lr;
            int irow = prow - 16;
            float4 v = {0.f, 0.f, 0.f, 0.f};
            if (irow >= 0 && irow < 256 && c4 >= 4 && c4 < 68)
                v = *(const float4*)(src + irow * 256 + 4 * c4 - 16);
            *(float4*)(dst + lr * 288 + 4 * c4) = v;
        }
        return;
    }
    for (int g = tid; g < 1360; g += 256) {
        int ch = g / 136;
        int w = g - ch * 136;
        int part = w / 17;
        int i = w - part * 17;
        const float* pr = psi_re + ch * 121;
        const float* pi = psi_im + ch * 121;
        float val = 0.f;
        if (part < 4) {
            int qmin = (part >= 2) ? 3 : 0;
            int comp = part & 1;
            float bden = blur[24];
            for (int q = qmin; q < 7; ++q) {
                int jj = i - q;
                if (jj < 0 || jj > 10) continue;
                float bq = blur[21 + q] / bden;
                float hh = comp ? pi[55 + jj] : pr[55 + jj];
                val += bq * hh;
            }
        } else {
            int pmin = (part >= 6) ? 3 : 0;
            int comp = part & 1;
            float dr = pr[60], di = pi[60];
            float inv = 1.f / (dr * dr + di * di);
            for (int p = pmin; p < 7; ++p) {
                int ii = i - p;
                if (ii < 0 || ii > 10) continue;
                float ap = blur[p * 7 + 3];
                float nr = pr[ii * 11 + 5], ni = pi[ii * 11 + 5];
                float f = comp ? (ni * dr - nr * di) * inv
                               : (nr * dr + ni * di) * inv;
                val += ap * f;
            }
        }
        fhp[g] = val;
    }
}

// ---------------- k_img: s0 + s1_out, one block per (Y, n) -----------------
__global__ __launch_bounds__(512, 2) void k_img(const float* __restrict__ pimg,
                                                const float* __restrict__ blur,
                                                const float* __restrict__ fhp,
                                                float* __restrict__ out) {
    __shared__ __align__(16) float bufA[5080];    // swizzled strip [17][W1]
    __shared__ __align__(16) float bufB[3600];    // 6 C planes
    const int tid = threadIdx.x;
    const int lane = tid & 63;
    const int wave = tid >> 6;
    const int Y = blockIdx.x;
    const int n = blockIdx.z;
    size_t nb = (size_t)n * 111 * 1024;

    // stage img strip rows 8Y-8.. cols -8..263, swizzled (zeros from pimg pad)
    const float* gp = pimg + n * PIMG_SZ + (8 * Y + 8) * 288 + 8;
    for (int idx = tid; idx < 17 * 68; idx += 512) {
        int r = idx / 68, c4 = idx - r * 68;
        float4 v = *(const float4*)(gp + r * 288 + 4 * c4);
        int c = 4 * c4;
        int d = r * W1 + c + (c >> 3);   // benign overlaps write zeros
        bufA[d] = v.x; bufA[d + 1] = v.y; bufA[d + 2] = v.z; bufA[d + 3] = v.w;
    }
    __syncthreads();

    // C phase: kh half-block; 3 planes per half; i-outer, 6 chains
    {
        int kh = __builtin_amdgcn_readfirstlane(wave >> 2);
        int fro = (Y == 0) ? 102 : 68;
        int fio = (Y == 0) ? 119 : 85;
        const float* fb = fhp + kh * 680;     // k = kh*5 + kk
        auto doC = [&](int t) {
            int tsw = t + (t >> 3);
            float cr0 = 0.f, ci0 = 0.f, cr1 = 0.f, ci1 = 0.f, cr2 = 0.f, ci2 = 0.f;
#pragma unroll
            for (int i = 0; i < 17; ++i) {
                float v = bufA[i * W1 + tsw];
                cr0 = fmaf(fb[fro + i], v, cr0);        ci0 = fmaf(fb[fio + i], v, ci0);
                cr1 = fmaf(fb[136 + fro + i], v, cr1);  ci1 = fmaf(fb[136 + fio + i], v, ci1);
                cr2 = fmaf(fb[272 + fro + i], v, cr2);  ci2 = fmaf(fb[272 + fio + i], v, ci2);
            }
            int p = kh * 3;
            bufB[p * CSTR + tsw] = cr0;       bufB[p * CSTR + 300 + tsw] = ci0;
            bufB[(p + 1) * CSTR + tsw] = cr1; bufB[(p + 1) * CSTR + 300 + tsw] = ci1;
            bufB[(p + 2) * CSTR + tsw] = cr2; bufB[(p + 2) * CSTR + 300 + tsw] = ci2;
        };
        doC(((wave & 3) << 6) + lane);
        if (lane < 9 && (wave == 0 || wave == 4)) doC(256 + lane);
    }
    __syncthreads();

    if (tid < 192) {          // out: 6 plane-sets x 32 X, partners via u±v
        int s = tid >> 5, X = tid & 31;
        int kdist = (s < 3) ? s : s + 2;
        const float* hb = fhp + kdist * 136 + ((X == 0) ? 34 : 0);
        const float* cR = bufB + s * CSTR + 9 * X;
        float u = 0.f, v2 = 0.f;
#pragma unroll
        for (int j = 0; j < 17; ++j) {
            int off = j + (j >> 3);
            u  = fmaf(hb[j], cR[off], u);
            v2 = fmaf(hb[17 + j], cR[off + 300], v2);
        }
        out[nb + (size_t)(1 + kdist) * 1024 + Y * 32 + X] = u - v2;
        if (s == 1 || s == 2 || s == 4 || s == 5) {
            int partner = (s < 3) ? 5 - s : 13 - s;
            out[nb + (size_t)(1 + partner) * 1024 + Y * 32 + X] = u + v2;
        }
    } else if (tid < 224) {   // s0: clipped 7x7 blur at stride 8
        int X = tid - 192;
        float s0 = 0.f;
#pragma unroll
        for (int p = 0; p < 7; ++p)
#pragma unroll
            for (int q = 0; q < 7; ++q) {
                int c = 8 * X + q + 5;
                s0 = fmaf(blur[p * 7 + q], bufA[(p + 5) * W1 + c + (c >> 3)], s0);
            }
        out[nb + Y * 32 + X] = s0;
    }
}

// ---------------- k_pairk: s2 for one psi-source pair, per (Y, pair, n) ----
__global__ __launch_bounds__(512, 4) void k_pairk(const float* __restrict__ pimg,
                                                  const float* __restrict__ psi_re,
                                                  const float* __restrict__ psi_im,
                                                  const float* __restrict__ fhp,
                                                  float* __restrict__ out) {
    __shared__ __align__(16) float bufA[10132];   // strip / s1a+s1b
    __shared__ __align__(16) float bufB[10200];   // Iv planes / C planes
    const int tid = threadIdx.x;
    const int lane = tid & 63;
    const int wave = tid >> 6;
    const int Y = blockIdx.x;
    const int pidx = blockIdx.y;   // 0..5
    const int n = blockIdx.z;
    size_t nb = (size_t)n * 111 * 1024;

    const int gtab_a[6] = {0, 5, 1, 2, 6, 7};
    const int gtab_b[6] = {0, 5, 4, 3, 9, 8};
    int ga = gtab_a[pidx], gb = gtab_b[pidx];

    const float* pr = psi_re + ga * 121;   // block-uniform -> s_load
    const float* pi = psi_im + ga * 121;
    float dr = pr[60], di = pi[60];
    float inv = rsqrtf(dr * dr + di * di);

    // stage strip [27][284]: img rows 8Y-13.., cols -8..263
    const float* gp = pimg + n * PIMG_SZ + (8 * Y + 3) * 288 + 8;
    for (int idx = tid; idx < 27 * 68; idx += 512) {
        int r = idx / 68, c4 = idx - r * 68;
        *(float4*)(bufA + r * SSTR + 4 * c4) = *(const float4*)(gp + r * 288 + 4 * c4);
    }
    __syncthreads();

    // Iv: lane = col v, 8 rows/task
    for (int task = tid; task < 532; task += 512) {
        int rg = (task >= 266) ? 1 : 0;
        int v = task - rg * 266;
        int r0 = rg * 8;
        const float* sp = bufA + r0 * SSTR + v + 3;
        float xv[18];
#pragma unroll
        for (int p = 0; p < 18; ++p) xv[p] = sp[p * SSTR];
        int dsw = v + (v >> 3);
        float* dR = bufB + r0 * IVSTR + dsw;
#pragma unroll
        for (int m = 0; m < 8; ++m) {
            float ar = 0.f, ai = 0.f;
#pragma unroll
            for (int p = 0; p < 11; ++p) {
                ar = fmaf(pr[p * 11 + 5], xv[m + p], ar);
                ai = fmaf(pi[p * 11 + 5], xv[m + p], ai);
            }
            dR[m * IVSTR] = ar;
            dR[m * IVSTR + IVPL] = ai;
        }
    }
    if (tid < 266) {                     // row 16
        int v = tid;
        const float* sp = bufA + 16 * SSTR + v + 3;
        float ar = 0.f, ai = 0.f;
#pragma unroll
        for (int p = 0; p < 11; ++p) {
            float x = sp[p * SSTR];
            ar = fmaf(pr[p * 11 + 5], x, ar);
            ai = fmaf(pi[p * 11 + 5], x, ai);
        }
        int dsw = v + (v >> 3);
        bufB[16 * IVSTR + dsw] = ar;
        bufB[16 * IVSTR + IVPL + dsw] = ai;
    }
    __syncthreads();

    // s1 pair: 4 shared real convs -> both channels
    int rowbase = 8 * Y - 8;
    for (int t2 = tid; t2 < 544; t2 += 512) {
        int r = t2 >> 5, xg = t2 & 31;
        int ry = rowbase + r;
        int wb = r * W1 + 9 * xg + 9;
        if (ry >= 0 && ry < 256) {
            const float* sR = bufB + r * IVSTR + 9 * xg;
            float xr[18], xi[18];
#pragma unroll
            for (int j = 0; j < 18; ++j) {
                int off = j + (j >> 3);
                xr[j] = sR[off];
                xi[j] = sR[off + IVPL];
            }
#pragma unroll
            for (int m = 0; m < 8; ++m) {
                float a = 0.f, b = 0.f, c = 0.f, d = 0.f;
#pragma unroll
                for (int j = 0; j < 11; ++j) {
                    float hr = pr[55 + j], hi2 = pi[55 + j];
                    a = fmaf(hr, xr[m + j], a);
                    b = fmaf(hi2, xi[m + j], b);
                    c = fmaf(hr, xi[m + j], c);
                    d = fmaf(hi2, xr[m + j], d);
                }
                float e1 = a - b, o1 = c + d;
                float e2 = a + b, o2 = c - d;
                bufA[wb + m]        = inv * sqrtf(fmaf(e1, e1, o1 * o1));
                bufA[S1SZ + wb + m] = inv * sqrtf(fmaf(e2, e2, o2 * o2));
            }
        } else {
#pragma unroll
            for (int m = 0; m < 8; ++m) {
                bufA[wb + m] = 0.f;
                bufA[S1SZ + wb + m] = 0.f;
            }
        }
    }
    if (tid < 17) {                      // edge zeros: t 0..7, t=264 slot
        int r = tid;
#pragma unroll
        for (int t = 0; t < 8; ++t) {
            bufA[r * W1 + t] = 0.f;
            bufA[S1SZ + r * W1 + t] = 0.f;
        }
        bufA[r * W1 + 297] = 0.f;
        bufA[S1SZ + r * W1 + 297] = 0.f;
    }
    __syncthreads();

    // C phase: i-outer, 12 named chains; kh = source half
    {
        int kh = __builtin_amdgcn_readfirstlane(wave >> 2);
        int fro = (Y == 0) ? 102 : 68;
        int fio = (Y == 0) ? 119 : 85;
        const float* s1b = bufA + kh * S1SZ;
        const float* f0 = fhp + 0 * 136, *f1 = fhp + 1 * 136, *f2 = fhp + 2 * 136;
        const float* f5 = fhp + 5 * 136, *f6 = fhp + 6 * 136, *f7 = fhp + 7 * 136;
        auto doC = [&](int t) {
            int tsw = t + (t >> 3);
            float cr0 = 0.f, ci0 = 0.f, cr1 = 0.f, ci1 = 0.f, cr2 = 0.f, ci2 = 0.f;
            float cr3 = 0.f, ci3 = 0.f, cr4 = 0.f, ci4 = 0.f, cr5 = 0.f, ci5 = 0.f;
#pragma unroll
            for (int i = 0; i < 17; ++i) {
                float v = s1b[i * W1 + tsw];
                cr0 = fmaf(f0[fro + i], v, cr0); ci0 = fmaf(f0[fio + i], v, ci0);
                cr1 = fmaf(f1[fro + i], v, cr1); ci1 = fmaf(f1[fio + i], v, ci1);
                cr2 = fmaf(f2[fro + i], v, cr2); ci2 = fmaf(f2[fio + i], v, ci2);
                cr3 = fmaf(f5[fro + i], v, cr3); ci3 = fmaf(f5[fio + i], v, ci3);
                cr4 = fmaf(f6[fro + i], v, cr4); ci4 = fmaf(f6[fio + i], v, ci4);
                cr5 = fmaf(f7[fro + i], v, cr5); ci5 = fmaf(f7[fio + i], v, ci5);
            }
            float* cb = bufB + kh * 6 * CSTR + tsw;
            cb[0] = cr0;          cb[300] = ci0;
            cb[CSTR] = cr1;       cb[CSTR + 300] = ci1;
            cb[2 * CSTR] = cr2;   cb[2 * CSTR + 300] = ci2;
            cb[3 * CSTR] = cr3;   cb[3 * CSTR + 300] = ci3;
            cb[4 * CSTR] = cr4;   cb[4 * CSTR + 300] = ci4;
            cb[5 * CSTR] = cr5;   cb[5 * CSTR + 300] = ci5;
        };
        doC(((wave & 3) << 6) + lane);
        if (lane < 9 && (wave == 0 || wave == 4)) doC(256 + lane);
    }
    __syncthreads();

    // out: 12 plane-sets (6 per source) x 32 X; partners via u±v
    if (tid < 384) {
        int chsel = (tid >= 192) ? 1 : 0;
        int t3 = tid - chsel * 192;
        int s = t3 >> 5, X = t3 & 31;
        int kdist = (s < 3) ? s : s + 2;
        int p = chsel * 6 + s;
        const float* hb = fhp + kdist * 136 + ((X == 0) ? 34 : 0);
        const float* cR = bufB + p * CSTR + 9 * X;
        float u = 0.f, v2 = 0.f;
#pragma unroll
        for (int j = 0; j < 17; ++j) {
            int off = j + (j >> 3);
            u  = fmaf(hb[j], cR[off], u);
            v2 = fmaf(hb[17 + j], cR[off + 300], v2);
        }
        int g = chsel ? gb : ga;
        int ch0 = 11 + g * 10;
        out[nb + (size_t)(ch0 + kdist) * 1024 + Y * 32 + X] = u - v2;
        if (s == 1 || s == 2 || s == 4 || s == 5) {
            int partner = (s < 3) ? 5 - s : 13 - s;
            out[nb + (size_t)(ch0 + partner) * 1024 + Y * 32 + X] = u + v2;
        }
    }
}

extern "C" void kernel_launch(void* const* d_in, const int* in_sizes, int n_in,
                              void* d_out, int out_size, void* d_ws, size_t ws_size,
                              hipStream_t stream) {
    const float* img    = (const float*)d_in[0];
    const float* psi_re = (const float*)d_in[1];
    const float* psi_im = (const float*)d_in[2];
    const float* blur   = (const float*)d_in[3];
    float* out = (float*)d_out;
    float* ws = (float*)d_ws;
    float* pimg = ws;
    float* fhp  = ws + FHP_OFF;

    k_prep<<<289, 256, 0, stream>>>(img, psi_re, psi_im, blur, pimg, fhp);

    dim3 gi(32, 1, 8);
    k_img<<<gi, 512, 0, stream>>>(pimg, blur, fhp, out);

    dim3 gpair(32, 6, 8);
    k_pairk<<<gpair, 512, 0, stream>>>(pimg, psi_re, psi_im, fhp, out);
}

// Round 17
// 59.740 us; speedup vs baseline: 2.2071x; 2.2071x over previous
//
#include <hip/hip_runtime.h>
#include <math.h>

// ---------------------------------------------------------------------------
// ScatteringNetwork — fused, rank-2 composed conv + theta-symmetry (R15 base).
//
// psi_k = F_k (x) H_k (rank-1). theta = pi*k/5: H3=H2, F3=conj(F2) (pairs
// (1,4),(2,3),(6,9),(7,8); k0,k5 real-H). Exploited:
//  - s1 pair blocks: both channels from 4 shared real convs
//  - C phase: C_conj = conj(C) -> only 6 distinct k planes {0,1,2,5,6,7}
//  - out phase: u=H'r*Cr, v=H'i*Ci -> out_k=u-v, out_partner=u+v
// Grid y: 7 = img, g0, g5, pair(1,4), pair(2,3), pair(6,9), pair(7,8).
//
// R17 = R15 + balanced C-phase tail: the 9 leftover t's (256..264) are
// distributed across ALL waves (plane-subset kk = wl, wl+4 per wave) instead
// of a full serial second doC on waves 0/4. Weight-live-set stays <=34
// (SGPR-resident) — the R16 instruction-explosion (204 live weights -> VMEM
// demotion) is avoided by construction.
//
// ws: [0) pimg 8*288*288 (border 16, zero) ; [663552) fhp 10*136
// fhp per ch: [0)H'r [17)H'i [34)H''r [51)H''i [68)F'r [85)F'i [102)F''r [119)F''i
// ---------------------------------------------------------------------------

#define PIMG_SZ (288 * 288)
#define FHP_OFF (8 * PIMG_SZ)
#define SSTR  284            // strip row stride (27 rows)
#define W1    298            // s1 swizzled row stride (t 0..264 -> tsw 0..297)
#define S1SZ  (17 * 298)     // per-channel s1 region
#define IVSTR 300            // Iv plane row stride
#define IVPL  (17 * 300)
#define CSTR  600            // C per-plane stride (re@0, im@300)

// ---------------- k_prep: padded img copy + factor table (proven) ----------
__global__ __launch_bounds__(256) void k_prep(const float* __restrict__ img,
                                              const float* __restrict__ psi_re,
                                              const float* __restrict__ psi_im,
                                              const float* __restrict__ blur,
                                              float* __restrict__ pimg,
                                              float* __restrict__ fhp) {
    int bid = blockIdx.x, tid = threadIdx.x;
    if (bid < 288) {
        int n = bid / 36, rg = bid - n * 36;
        float* dst = pimg + n * PIMG_SZ + rg * 8 * 288;
        const float* src = img + n * 65536;
        for (int i = tid; i < 576; i += 256) {
            int lr = i / 72, c4 = i - lr * 72;
            int prow = rg * 8 + lr;
            int irow = prow - 16;
            float4 v = {0.f, 0.f, 0.f, 0.f};
            if (irow >= 0 && irow < 256 && c4 >= 4 && c4 < 68)
                v = *(const float4*)(src + irow * 256 + 4 * c4 - 16);
            *(float4*)(dst + lr * 288 + 4 * c4) = v;
        }
        return;
    }
    for (int g = tid; g < 1360; g += 256) {
        int ch = g / 136;
        int w = g - ch * 136;
        int part = w / 17;
        int i = w - part * 17;
        const float* pr = psi_re + ch * 121;
        const float* pi = psi_im + ch * 121;
        float val = 0.f;
        if (part < 4) {                       // H-type
            int qmin = (part >= 2) ? 3 : 0;
            int comp = part & 1;
            float bden = blur[24];
            for (int q = qmin; q < 7; ++q) {
                int jj = i - q;
                if (jj < 0 || jj > 10) continue;
                float bq = blur[21 + q] / bden;
                float hh = comp ? pi[55 + jj] : pr[55 + jj];
                val += bq * hh;
            }
        } else {                              // F-type
            int pmin = (part >= 6) ? 3 : 0;
            int comp = part & 1;
            float dr = pr[60], di = pi[60];
            float inv = 1.f / (dr * dr + di * di);
            for (int p = pmin; p < 7; ++p) {
                int ii = i - p;
                if (ii < 0 || ii > 10) continue;
                float ap = blur[p * 7 + 3];
                float nr = pr[ii * 11 + 5], ni = pi[ii * 11 + 5];
                float f = comp ? (ni * dr - nr * di) * inv
                               : (nr * dr + ni * di) * inv;
                val += ap * f;
            }
        }
        fhp[g] = val;
    }
}

// ---------------- k_fused4: one block per (Y, src2, n), 512 thr ------------
__global__ __launch_bounds__(512, 4) void k_fused4(const float* __restrict__ pimg,
                                                   const float* __restrict__ psi_re,
                                                   const float* __restrict__ psi_im,
                                                   const float* __restrict__ blur,
                                                   const float* __restrict__ fhp,
                                                   float* __restrict__ out) {
    __shared__ __align__(16) float bufA[10132];   // strip / s1a+s1b
    __shared__ __align__(16) float bufB[10200];   // Iv planes / C planes
    const int tid = threadIdx.x;
    const int lane = tid & 63;
    const int wave = tid >> 6;
    const int Y = blockIdx.x;
    const int src2 = blockIdx.y;    // 0 img, 1 g0, 2 g5, 3..6 pairs
    const int n = blockIdx.z;
    size_t nb = (size_t)n * 111 * 1024;

    const bool isimg = (src2 == 0);
    const bool paired = (src2 >= 3);
    int ga = 0, gb = 0;
    if (src2 == 1) ga = gb = 0;
    else if (src2 == 2) ga = gb = 5;
    else if (paired) {
        int p2 = src2 - 3;
        ga = (p2 < 2) ? 1 + p2 : 4 + p2;      // 1,2,6,7
        gb = (p2 < 2) ? 4 - p2 : 11 - p2;     // 4,3,9,8
    }

    if (isimg) {
        // stage img strip [17 rows] swizzled into W1 layout (zeros from pimg pad)
        const float* gp = pimg + n * PIMG_SZ + (8 * Y + 8) * 288 + 8;
        for (int idx = tid; idx < 17 * 68; idx += 512) {
            int r = idx / 68, c4 = idx - r * 68;
            float4 v = *(const float4*)(gp + r * 288 + 4 * c4);
            int c = 4 * c4;
            int d = r * W1 + c + (c >> 3);
            bufA[d] = v.x; bufA[d + 1] = v.y; bufA[d + 2] = v.z; bufA[d + 3] = v.w;
        }
    } else {
        const float* pr = psi_re + ga * 121;   // block-uniform -> s_load
        const float* pi = psi_im + ga * 121;
        float dr = pr[60], di = pi[60];
        float inv = rsqrtf(dr * dr + di * di);

        // stage strip [27][284]
        const float* gp = pimg + n * PIMG_SZ + (8 * Y + 3) * 288 + 8;
        for (int idx = tid; idx < 27 * 68; idx += 512) {
            int r = idx / 68, c4 = idx - r * 68;
            *(float4*)(bufA + r * SSTR + 4 * c4) = *(const float4*)(gp + r * 288 + 4 * c4);
        }
        __syncthreads();

        // Iv: lane = col v, 8 rows/task (conflict-free strip reads)
        for (int task = tid; task < 532; task += 512) {
            int rg = (task >= 266) ? 1 : 0;
            int v = task - rg * 266;
            int r0 = rg * 8;
            const float* sp = bufA + r0 * SSTR + v + 3;
            float xv[18];
#pragma unroll
            for (int p = 0; p < 18; ++p) xv[p] = sp[p * SSTR];
            int dsw = v + (v >> 3);
            float* dR = bufB + r0 * IVSTR + dsw;
#pragma unroll
            for (int m = 0; m < 8; ++m) {
                float ar = 0.f, ai = 0.f;
#pragma unroll
                for (int p = 0; p < 11; ++p) {
                    ar = fmaf(pr[p * 11 + 5], xv[m + p], ar);
                    ai = fmaf(pi[p * 11 + 5], xv[m + p], ai);
                }
                dR[m * IVSTR] = ar;
                dR[m * IVSTR + IVPL] = ai;
            }
        }
        if (tid < 266) {
            int v = tid;
            const float* sp = bufA + 16 * SSTR + v + 3;
            float ar = 0.f, ai = 0.f;
#pragma unroll
            for (int p = 0; p < 11; ++p) {
                float x = sp[p * SSTR];
                ar = fmaf(pr[p * 11 + 5], x, ar);
                ai = fmaf(pi[p * 11 + 5], x, ai);
            }
            int dsw = v + (v >> 3);
            bufB[16 * IVSTR + dsw] = ar;
            bufB[16 * IVSTR + IVPL + dsw] = ai;
        }
        __syncthreads();

        // s1: tasks (r, 8-col group). paired -> 4 shared real convs, 2 outputs
        int rowbase = 8 * Y - 8;
        for (int t2 = tid; t2 < 544; t2 += 512) {
            int r = t2 >> 5, xg = t2 & 31;
            int ry = rowbase + r;
            int wb = r * W1 + 9 * xg + 9;
            if (ry >= 0 && ry < 256) {
                const float* sR = bufB + r * IVSTR + 9 * xg;
                float xr[18], xi[18];
#pragma unroll
                for (int j = 0; j < 18; ++j) {
                    int off = j + (j >> 3);
                    xr[j] = sR[off];
                    xi[j] = sR[off + IVPL];
                }
                if (paired) {
#pragma unroll
                    for (int m = 0; m < 8; ++m) {
                        float a = 0.f, b = 0.f, c = 0.f, d = 0.f;
#pragma unroll
                        for (int j = 0; j < 11; ++j) {
                            float hr = pr[55 + j], hi2 = pi[55 + j];
                            a = fmaf(hr, xr[m + j], a);
                            b = fmaf(hi2, xi[m + j], b);
                            c = fmaf(hr, xi[m + j], c);
                            d = fmaf(hi2, xr[m + j], d);
                        }
                        float e1 = a - b, o1 = c + d;
                        float e2 = a + b, o2 = c - d;
                        bufA[wb + m]        = inv * sqrtf(fmaf(e1, e1, o1 * o1));
                        bufA[S1SZ + wb + m] = inv * sqrtf(fmaf(e2, e2, o2 * o2));
                    }
                } else {
#pragma unroll
                    for (int m = 0; m < 8; ++m) {
                        float sr = 0.f, si = 0.f;
#pragma unroll
                        for (int j = 0; j < 11; ++j) {
                            float hr = pr[55 + j], hi2 = pi[55 + j];
                            sr = fmaf(hr, xr[m + j], fmaf(-hi2, xi[m + j], sr));
                            si = fmaf(hr, xi[m + j], fmaf(hi2, xr[m + j], si));
                        }
                        bufA[wb + m] = inv * sqrtf(fmaf(sr, sr, si * si));
                    }
                }
            } else {
#pragma unroll
                for (int m = 0; m < 8; ++m) {
                    bufA[wb + m] = 0.f;
                    if (paired) bufA[S1SZ + wb + m] = 0.f;
                }
            }
        }
        if (tid < 17) {                      // edge zeros: t 0..7 and t 264 slot
            int r = tid;
#pragma unroll
            for (int t = 0; t < 8; ++t) {
                bufA[r * W1 + t] = 0.f;
                if (paired) bufA[S1SZ + r * W1 + t] = 0.f;
            }
            bufA[r * W1 + 297] = 0.f;
            if (paired) bufA[S1SZ + r * W1 + 297] = 0.f;
        }
    }
    __syncthreads();

    // ---- C phase: 6 distinct k (conj-trick); kh = wave half selects src ----
    {
        int kh = __builtin_amdgcn_readfirstlane(wave >> 2);   // 0 or 1
        int wl = wave & 3;                                    // wave-uniform
        int fro = (Y == 0) ? 102 : 68;
        int fio = (Y == 0) ? 119 : 85;
        const float* s1base = bufA + (paired ? kh * S1SZ : 0);
        int nk = paired ? 6 : 3;

        // main pass: t 0..255 (4 waves per half, 64 t each), nk planes
        {
            int t = (wl << 6) + lane;
            int tsw = t + (t >> 3);
            float v[17];
#pragma unroll
            for (int i = 0; i < 17; ++i) v[i] = s1base[i * W1 + tsw];
            for (int kk = 0; kk < nk; ++kk) {     // uniform bound; <=34 wts live
                int k, p;
                if (paired) { k = (kk < 3) ? kk : kk + 2; p = kh * 6 + kk; }
                else        { k = kh * 5 + kk;            p = kh * 3 + kk; }
                const float* fR = fhp + k * 136 + fro;   // uniform -> s_load
                const float* fI = fhp + k * 136 + fio;
                float cr = 0.f, ci = 0.f;
#pragma unroll
                for (int i = 0; i < 17; ++i) {
                    cr = fmaf(fR[i], v[i], cr);
                    ci = fmaf(fI[i], v[i], ci);
                }
                bufB[p * CSTR + tsw] = cr;
                bufB[p * CSTR + 300 + tsw] = ci;
            }
        }
        // balanced tail: t 256..264; each wave covers planes kk = wl, wl+4
        if (lane < 9) {
            int t = 256 + lane;
            int tsw = t + (t >> 3);
            float v[17];
#pragma unroll
            for (int i = 0; i < 17; ++i) v[i] = s1base[i * W1 + tsw];
            for (int kk = wl; kk < nk; kk += 4) { // uniform (wl wave-uniform)
                int k, p;
                if (paired) { k = (kk < 3) ? kk : kk + 2; p = kh * 6 + kk; }
                else        { k = kh * 5 + kk;            p = kh * 3 + kk; }
                const float* fR = fhp + k * 136 + fro;
                const float* fI = fhp + k * 136 + fio;
                float cr = 0.f, ci = 0.f;
#pragma unroll
                for (int i = 0; i < 17; ++i) {
                    cr = fmaf(fR[i], v[i], cr);
                    ci = fmaf(fI[i], v[i], ci);
                }
                bufB[p * CSTR + tsw] = cr;
                bufB[p * CSTR + 300 + tsw] = ci;
            }
        }
    }
    __syncthreads();

    // ---- out phase: 6 conv-sets per channel; pairs get 2 outputs ----
    int nout = paired ? 384 : 192;
    if (tid < nout) {
        int chsel = paired ? (tid >= 192) : 0;
        int t3 = tid - chsel * 192;
        int s = t3 >> 5, X = t3 & 31;
        int kdist = (s < 3) ? s : s + 2;             // {0,1,2,5,6,7}
        int p = chsel * 6 + s;
        const float* hb = fhp + kdist * 136 + ((X == 0) ? 34 : 0);
        const float* cR = bufB + p * CSTR + 9 * X;
        float u = 0.f, v2 = 0.f;
#pragma unroll
        for (int j = 0; j < 17; ++j) {
            int off = j + (j >> 3);
            u  = fmaf(hb[j], cR[off], u);
            v2 = fmaf(hb[17 + j], cR[off + 300], v2);
        }
        int g = chsel ? gb : ga;
        int ch0 = isimg ? 1 : 11 + g * 10;
        out[nb + (size_t)(ch0 + kdist) * 1024 + Y * 32 + X] = u - v2;
        if (s == 1 || s == 2 || s == 4 || s == 5) {
            int partner = (s < 3) ? 5 - s : 13 - s;  // 4,3,9,8
            out[nb + (size_t)(ch0 + partner) * 1024 + Y * 32 + X] = u + v2;
        }
    } else if (isimg && tid < 224) {                 // s0: clipped 7x7 blur
        int X = tid - 192;
        float s0 = 0.f;
#pragma unroll
        for (int p = 0; p < 7; ++p)
#pragma unroll
            for (int q = 0; q < 7; ++q) {
                int c = 8 * X + q + 5;
                s0 = fmaf(blur[p * 7 + q], bufA[(p + 5) * W1 + c + (c >> 3)], s0);
            }
        out[nb + Y * 32 + X] = s0;
    }
}

extern "C" void kernel_launch(void* const* d_in, const int* in_sizes, int n_in,
                              void* d_out, int out_size, void* d_ws, size_t ws_size,
                              hipStream_t stream) {
    const float* img    = (const float*)d_in[0];
    const float* psi_re = (const float*)d_in[1];
    const float* psi_im = (const float*)d_in[2];
    const float* blur   = (const float*)d_in[3];
    float* out = (float*)d_out;
    float* ws = (float*)d_ws;
    float* pimg = ws;
    float* fhp  = ws + FHP_OFF;

    k_prep<<<289, 256, 0, stream>>>(img, psi_re, psi_im, blur, pimg, fhp);

    dim3 g2(32, 7, 8);
    k_fused4<<<g2, 512, 0, stream>>>(pimg, psi_re, psi_im, blur, fhp, out);
}

// Round 18
// 58.783 us; speedup vs baseline: 2.2430x; 1.0163x over previous
//
#include <hip/hip_runtime.h>
#include <math.h>

// ---------------------------------------------------------------------------
// ScatteringNetwork — fused, rank-2 composed conv + theta-symmetry (R15/R17
// base) + R18 LDS diet: interior tensors (Iv, s1) stored as bf16 PAIRS packed
// in u32 (Iv: re|im, s1: chanA|chanB; degenerate sources store (v,v)), and C
// computed per-source (6 planes) in a source loop. LDS 81.4 -> 50.2 KB ->
// 3 blocks/CU (24 waves, +50% latency hiding). C/out stay fp32; weights stay
// SGPR (s_load). Also fixes the img-path staging slot-collision (both
// colliding writers now write 0).
//
// psi_k = F_k (x) H_k (rank-1). theta = pi*k/5 -> H3=H2, F3=conj(F2) (pairs
// (1,4),(2,3),(6,9),(7,8); k0,k5 real-H):
//  - s1 pair blocks: both channels from 4 shared real convs
//  - C: conj-trick -> 6 distinct planes {0,1,2,5,6,7}
//  - out: u=H'r*Cr, v=H'i*Ci -> out_k=u-v, out_partner=u+v
// Grid y: 7 = img, g0, g5, pair(1,4), pair(2,3), pair(6,9), pair(7,8).
//
// ws: [0) pimg 8*288*288 (border 16, zero) ; [663552) fhp 10*136
// fhp per ch: [0)H'r [17)H'i [34)H''r [51)H''i [68)F'r [85)F'i [102)F''r [119)F''i
// ---------------------------------------------------------------------------

#define PIMG_SZ (288 * 288)
#define FHP_OFF (8 * PIMG_SZ)
#define SSTR  276            // fp32 strip row stride (27 rows, s2 path)
#define W1    298            // packed s1 row stride (u32 slots, 17 rows)
#define IVSTR 300            // packed Iv row stride (u32 slots, 17 rows)
#define CSTR  600            // C fp32 per-plane stride (re@0, im@300), 6 planes

static __device__ __forceinline__ unsigned packbf2(float a, float b) {
    unsigned ua = __float_as_uint(a);
    unsigned ub = __float_as_uint(b);
    ua = (ua + 0x7FFFu + ((ua >> 16) & 1u)) >> 16;          // RNE bf16, lo
    ub = (ub + 0x7FFFu + ((ub >> 16) & 1u)) & 0xFFFF0000u;  // RNE bf16, hi
    return ua | ub;
}
static __device__ __forceinline__ float unplo(unsigned u) { return __uint_as_float(u << 16); }
static __device__ __forceinline__ float unphi(unsigned u) { return __uint_as_float(u & 0xFFFF0000u); }

// ---------------- k_prep: padded img copy + factor table (proven) ----------
__global__ __launch_bounds__(256) void k_prep(const float* __restrict__ img,
                                              const float* __restrict__ psi_re,
                                              const float* __restrict__ psi_im,
                                              const float* __restrict__ blur,
                                              float* __restrict__ pimg,
                                              float* __restrict__ fhp) {
    int bid = blockIdx.x, tid = threadIdx.x;
    if (bid < 288) {
        int n = bid / 36, rg = bid - n * 36;
        float* dst = pimg + n * PIMG_SZ + rg * 8 * 288;
        const float* src = img + n * 65536;
        for (int i = tid; i < 576; i += 256) {
            int lr = i / 72, c4 = i - lr * 72;
            int prow = rg * 8 + lr;
            int irow = prow - 16;
            float4 v = {0.f, 0.f, 0.f, 0.f};
            if (irow >= 0 && irow < 256 && c4 >= 4 && c4 < 68)
                v = *(const float4*)(src + irow * 256 + 4 * c4 - 16);
            *(float4*)(dst + lr * 288 + 4 * c4) = v;
        }
        return;
    }
    for (int g = tid; g < 1360; g += 256) {
        int ch = g / 136;
        int w = g - ch * 136;
        int part = w / 17;
        int i = w - part * 17;
        const float* pr = psi_re + ch * 121;
        const float* pi = psi_im + ch * 121;
        float val = 0.f;
        if (part < 4) {                       // H-type
            int qmin = (part >= 2) ? 3 : 0;
            int comp = part & 1;
            float bden = blur[24];
            for (int q = qmin; q < 7; ++q) {
                int jj = i - q;
                if (jj < 0 || jj > 10) continue;
                float bq = blur[21 + q] / bden;
                float hh = comp ? pi[55 + jj] : pr[55 + jj];
                val += bq * hh;
            }
        } else {                              // F-type
            int pmin = (part >= 6) ? 3 : 0;
            int comp = part & 1;
            float dr = pr[60], di = pi[60];
            float inv = 1.f / (dr * dr + di * di);
            for (int p = pmin; p < 7; ++p) {
                int ii = i - p;
                if (ii < 0 || ii > 10) continue;
                float ap = blur[p * 7 + 3];
                float nr = pr[ii * 11 + 5], ni = pi[ii * 11 + 5];
                float f = comp ? (ni * dr - nr * di) * inv
                               : (nr * dr + ni * di) * inv;
                val += ap * f;
            }
        }
        fhp[g] = val;
    }
}

// ---------------- k_fused5: one block per (Y, src2, n), 512 thr ------------
__global__ __launch_bounds__(512, 6) void k_fused5(const float* __restrict__ pimg,
                                                   const float* __restrict__ psi_re,
                                                   const float* __restrict__ psi_im,
                                                   const float* __restrict__ blur,
                                                   const float* __restrict__ fhp,
                                                   float* __restrict__ out) {
    __shared__ __align__(16) float bufA[7452];   // fp32 strip [27][276] / packed s1 [17][298]
    __shared__ __align__(16) float bufB[5100];   // packed Iv [17][300] / C fp32 6*600
    unsigned* s1P = (unsigned*)bufA;
    unsigned* ivP = (unsigned*)bufB;
    const int tid = threadIdx.x;
    const int lane = tid & 63;
    const int wave = tid >> 6;
    const int Y = blockIdx.x;
    const int src2 = blockIdx.y;    // 0 img, 1 g0, 2 g5, 3..6 pairs
    const int n = blockIdx.z;
    size_t nb = (size_t)n * 111 * 1024;

    const bool isimg = (src2 == 0);
    const bool paired = (src2 >= 3);
    int ga = 0, gb = 0;
    if (src2 == 1) ga = gb = 0;
    else if (src2 == 2) ga = gb = 5;
    else if (paired) {
        int p2 = src2 - 3;
        ga = (p2 < 2) ? 1 + p2 : 4 + p2;      // 1,2,6,7
        gb = (p2 < 2) ? 4 - p2 : 11 - p2;     // 4,3,9,8
    }

    if (isimg) {
        // stage img strip [17 rows] packed (v,v) into W1 layout; cols >264
        // zeroed (they alias row r+1 t0..6 slots — both must be 0)
        const float* gp = pimg + n * PIMG_SZ + (8 * Y + 8) * 288 + 8;
        for (int idx = tid; idx < 17 * 68; idx += 512) {
            int r = idx / 68, c4 = idx - r * 68;
            float4 v = *(const float4*)(gp + r * 288 + 4 * c4);
            int c = 4 * c4;
            int d = r * W1 + c + (c >> 3);   // (c>>3) constant within a float4
            float vs[4] = {v.x, v.y, v.z, v.w};
#pragma unroll
            for (int e = 0; e < 4; ++e) {
                float val = (c + e > 264) ? 0.f : vs[e];
                s1P[d + e] = packbf2(val, val);
            }
        }
    } else {
        const float* pr = psi_re + ga * 121;   // block-uniform -> s_load
        const float* pi = psi_im + ga * 121;
        float dr = pr[60], di = pi[60];
        float inv = rsqrtf(dr * dr + di * di);

        // stage fp32 strip [27][276]: img rows 8Y-13.., cols -8..263
        const float* gp = pimg + n * PIMG_SZ + (8 * Y + 3) * 288 + 8;
        for (int idx = tid; idx < 27 * 68; idx += 512) {
            int r = idx / 68, c4 = idx - r * 68;
            *(float4*)(bufA + r * SSTR + 4 * c4) = *(const float4*)(gp + r * 288 + 4 * c4);
        }
        __syncthreads();

        // Iv packed (re|im): lane = col v, 8 rows/task (conflict-free reads)
        for (int task = tid; task < 532; task += 512) {
            int rg = (task >= 266) ? 1 : 0;
            int v = task - rg * 266;
            int r0 = rg * 8;
            const float* sp = bufA + r0 * SSTR + v + 3;
            float xv[18];
#pragma unroll
            for (int p = 0; p < 18; ++p) xv[p] = sp[p * SSTR];
            int dsw = v + (v >> 3);
            unsigned* dP = ivP + r0 * IVSTR + dsw;
#pragma unroll
            for (int m = 0; m < 8; ++m) {
                float ar = 0.f, ai = 0.f;
#pragma unroll
                for (int p = 0; p < 11; ++p) {
                    ar = fmaf(pr[p * 11 + 5], xv[m + p], ar);
                    ai = fmaf(pi[p * 11 + 5], xv[m + p], ai);
                }
                dP[m * IVSTR] = packbf2(ar, ai);
            }
        }
        if (tid < 266) {                     // row 16
            int v = tid;
            const float* sp = bufA + 16 * SSTR + v + 3;
            float ar = 0.f, ai = 0.f;
#pragma unroll
            for (int p = 0; p < 11; ++p) {
                float x = sp[p * SSTR];
                ar = fmaf(pr[p * 11 + 5], x, ar);
                ai = fmaf(pi[p * 11 + 5], x, ai);
            }
            ivP[16 * IVSTR + v + (v >> 3)] = packbf2(ar, ai);
        }
        __syncthreads();

        // s1 packed (chanA|chanB): 18 packed reads -> 36 values
        int rowbase = 8 * Y - 8;
        for (int t2 = tid; t2 < 544; t2 += 512) {
            int r = t2 >> 5, xg = t2 & 31;
            int ry = rowbase + r;
            int wb = r * W1 + 9 * xg + 9;
            if (ry >= 0 && ry < 256) {
                const unsigned* sP = ivP + r * IVSTR + 9 * xg;
                float xr[18], xi[18];
#pragma unroll
                for (int j = 0; j < 18; ++j) {
                    unsigned u = sP[j + (j >> 3)];
                    xr[j] = unplo(u);
                    xi[j] = unphi(u);
                }
                if (paired) {
#pragma unroll
                    for (int m = 0; m < 8; ++m) {
                        float a = 0.f, b = 0.f, c = 0.f, d = 0.f;
#pragma unroll
                        for (int j = 0; j < 11; ++j) {
                            float hr = pr[55 + j], hi2 = pi[55 + j];
                            a = fmaf(hr, xr[m + j], a);
                            b = fmaf(hi2, xi[m + j], b);
                            c = fmaf(hr, xi[m + j], c);
                            d = fmaf(hi2, xr[m + j], d);
                        }
                        float e1 = a - b, o1 = c + d;
                        float e2 = a + b, o2 = c - d;
                        s1P[wb + m] = packbf2(inv * sqrtf(fmaf(e1, e1, o1 * o1)),
                                              inv * sqrtf(fmaf(e2, e2, o2 * o2)));
                    }
                } else {
#pragma unroll
                    for (int m = 0; m < 8; ++m) {
                        float sr = 0.f, si = 0.f;
#pragma unroll
                        for (int j = 0; j < 11; ++j) {
                            float hr = pr[55 + j], hi2 = pi[55 + j];
                            sr = fmaf(hr, xr[m + j], fmaf(-hi2, xi[m + j], sr));
                            si = fmaf(hr, xi[m + j], fmaf(hi2, xr[m + j], si));
                        }
                        float val = inv * sqrtf(fmaf(sr, sr, si * si));
                        s1P[wb + m] = packbf2(val, val);
                    }
                }
            } else {
#pragma unroll
                for (int m = 0; m < 8; ++m) s1P[wb + m] = 0u;
            }
        }
        if (tid < 17) {                      // edge zeros: t 0..7 and t 264 slot
            int r = tid;
#pragma unroll
            for (int t = 0; t < 8; ++t) s1P[r * W1 + t] = 0u;
            s1P[r * W1 + 297] = 0u;
        }
    }
    __syncthreads();

    // ---- per-source: C (6 planes fp32, overwrites Iv) then out ----
    const int nsrc = paired ? 2 : 1;
    for (int sh = 0; sh < nsrc; ++sh) {
        {
            int kh = __builtin_amdgcn_readfirstlane(wave >> 2);   // plane half
            int wl = wave & 3;
            int fro = (Y == 0) ? 102 : 68;
            int fio = (Y == 0) ? 119 : 85;
            {   // main pass: t 0..255
                int t = (wl << 6) + lane;
                int tsw = t + (t >> 3);
                float v[17];
#pragma unroll
                for (int i = 0; i < 17; ++i) {
                    unsigned u = s1P[i * W1 + tsw];
                    v[i] = sh ? unphi(u) : unplo(u);
                }
                for (int kk = 0; kk < 3; ++kk) {      // <=34 weights live
                    int k = kh * 5 + kk;              // {0,1,2} / {5,6,7}
                    int p = kh * 3 + kk;
                    const float* fR = fhp + k * 136 + fro;   // uniform -> s_load
                    const float* fI = fhp + k * 136 + fio;
                    float cr = 0.f, ci = 0.f;
#pragma unroll
                    for (int i = 0; i < 17; ++i) {
                        cr = fmaf(fR[i], v[i], cr);
                        ci = fmaf(fI[i], v[i], ci);
                    }
                    bufB[p * CSTR + tsw] = cr;
                    bufB[p * CSTR + 300 + tsw] = ci;
                }
            }
            int wv = __builtin_amdgcn_readfirstlane(wave);
            if (wv < 6 && lane < 9) {                 // balanced tail t 256..264
                int t = 256 + lane;
                int tsw = t + (t >> 3);
                float v[17];
#pragma unroll
                for (int i = 0; i < 17; ++i) {
                    unsigned u = s1P[i * W1 + tsw];
                    v[i] = sh ? unphi(u) : unplo(u);
                }
                int k = (wv < 3) ? wv : wv + 2;
                const float* fR = fhp + k * 136 + fro;
                const float* fI = fhp + k * 136 + fio;
                float cr = 0.f, ci = 0.f;
#pragma unroll
                for (int i = 0; i < 17; ++i) {
                    cr = fmaf(fR[i], v[i], cr);
                    ci = fmaf(fI[i], v[i], ci);
                }
                bufB[wv * CSTR + tsw] = cr;
                bufB[wv * CSTR + 300 + tsw] = ci;
            }
        }
        __syncthreads();

        if (tid < 192) {          // out: 6 plane-sets x 32 X, partners via u±v
            int s = tid >> 5, X = tid & 31;
            int kdist = (s < 3) ? s : s + 2;          // {0,1,2,5,6,7}
            const float* hb = fhp + kdist * 136 + ((X == 0) ? 34 : 0);
            const float* cR = bufB + s * CSTR + 9 * X;
            float u = 0.f, v2 = 0.f;
#pragma unroll
            for (int j = 0; j < 17; ++j) {
                int off = j + (j >> 3);
                u  = fmaf(hb[j], cR[off], u);
                v2 = fmaf(hb[17 + j], cR[off + 300], v2);
            }
            int g = sh ? gb : ga;
            int ch0 = isimg ? 1 : 11 + g * 10;
            out[nb + (size_t)(ch0 + kdist) * 1024 + Y * 32 + X] = u - v2;
            if (s == 1 || s == 2 || s == 4 || s == 5) {
                int partner = (s < 3) ? 5 - s : 13 - s;   // 4,3,9,8
                out[nb + (size_t)(ch0 + partner) * 1024 + Y * 32 + X] = u + v2;
            }
        } else if (isimg && tid < 224) {              // s0: clipped 7x7 blur
            int X = tid - 192;
            float s0 = 0.f;
#pragma unroll
            for (int p = 0; p < 7; ++p)
#pragma unroll
                for (int q = 0; q < 7; ++q) {
                    int c = 8 * X + q + 5;
                    s0 = fmaf(blur[p * 7 + q],
                              unplo(s1P[(p + 5) * W1 + c + (c >> 3)]), s0);
                }
            out[nb + Y * 32 + X] = s0;
        }
        if (sh + 1 < nsrc) __syncthreads();
    }
}

extern "C" void kernel_launch(void* const* d_in, const int* in_sizes, int n_in,
                              void* d_out, int out_size, void* d_ws, size_t ws_size,
                              hipStream_t stream) {
    const float* img    = (const float*)d_in[0];
    const float* psi_re = (const float*)d_in[1];
    const float* psi_im = (const float*)d_in[2];
    const float* blur   = (const float*)d_in[3];
    float* out = (float*)d_out;
    float* ws = (float*)d_ws;
    float* pimg = ws;
    float* fhp  = ws + FHP_OFF;

    k_prep<<<289, 256, 0, stream>>>(img, psi_re, psi_im, blur, pimg, fhp);

    dim3 g2(32, 7, 8);
    k_fused5<<<g2, 512, 0, stream>>>(pimg, psi_re, psi_im, blur, fhp, out);
}

// Round 19
// 51.152 us; speedup vs baseline: 2.5776x; 1.1492x over previous
//
#include <hip/hip_runtime.h>
#include <math.h>

// ---------------------------------------------------------------------------
// ScatteringNetwork — fused, rank-2 composed conv + theta-symmetry
// (R15/R17/R18 base). R19: pimg ELIMINATED — staging reads img directly with
// float4 predicates (R12-proven pattern); k_prep shrinks to fhp-only (tiny).
// Removes ~5-6 us of serial prologue (pimg copy + its launch gap).
//
// Interior tensors (Iv, s1) bf16-packed in u32 (Iv: re|im, s1: chanA|chanB;
// degenerate sources store (v,v)); C computed per-source (6 planes fp32).
// LDS 50.2 KB -> 3 blocks/CU. Weights SGPR (s_load).
//
// psi_k = F_k (x) H_k (rank-1). theta = pi*k/5 -> H3=H2, F3=conj(F2) (pairs
// (1,4),(2,3),(6,9),(7,8); k0,k5 real-H):
//  - s1 pair blocks: both channels from 4 shared real convs
//  - C: conj-trick -> 6 distinct planes {0,1,2,5,6,7}
//  - out: u=H'r*Cr, v=H'i*Ci -> out_k=u-v, out_partner=u+v
// Grid y: 7 = img, g0, g5, pair(1,4), pair(2,3), pair(6,9), pair(7,8).
//
// ws: [0) fhp 10*136 floats only.
// fhp per ch: [0)H'r [17)H'i [34)H''r [51)H''i [68)F'r [85)F'i [102)F''r [119)F''i
// ---------------------------------------------------------------------------

#define W1    298            // packed s1 row stride (u32 slots, 17 rows)
#define SSTR  276            // fp32 strip row stride (27 rows, s2 path)
#define IVSTR 300            // packed Iv row stride (u32 slots, 17 rows)
#define CSTR  600            // C fp32 per-plane stride (re@0, im@300), 6 planes

static __device__ __forceinline__ unsigned packbf2(float a, float b) {
    unsigned ua = __float_as_uint(a);
    unsigned ub = __float_as_uint(b);
    ua = (ua + 0x7FFFu + ((ua >> 16) & 1u)) >> 16;          // RNE bf16, lo
    ub = (ub + 0x7FFFu + ((ub >> 16) & 1u)) & 0xFFFF0000u;  // RNE bf16, hi
    return ua | ub;
}
static __device__ __forceinline__ float unplo(unsigned u) { return __uint_as_float(u << 16); }
static __device__ __forceinline__ float unphi(unsigned u) { return __uint_as_float(u & 0xFFFF0000u); }

// ---------------- k_fhp: composed factor table only (tiny) -----------------
__global__ void k_fhp(const float* __restrict__ psi_re,
                      const float* __restrict__ psi_im,
                      const float* __restrict__ blur,
                      float* __restrict__ fhp) {
    int g = blockIdx.x * 64 + threadIdx.x;
    if (g >= 1360) return;
    int ch = g / 136;
    int w = g - ch * 136;
    int part = w / 17;
    int i = w - part * 17;
    const float* pr = psi_re + ch * 121;
    const float* pi = psi_im + ch * 121;
    float val = 0.f;
    if (part < 4) {                       // H-type: H_j = psi[5][j]
        int qmin = (part >= 2) ? 3 : 0;
        int comp = part & 1;
        float bden = blur[24];
        for (int q = qmin; q < 7; ++q) {
            int jj = i - q;
            if (jj < 0 || jj > 10) continue;
            float bq = blur[21 + q] / bden;
            float hh = comp ? pi[55 + jj] : pr[55 + jj];
            val += bq * hh;
        }
    } else {                              // F-type: F_i = psi[i][5]/psi[5][5]
        int pmin = (part >= 6) ? 3 : 0;
        int comp = part & 1;
        float dr = pr[60], di = pi[60];
        float inv = 1.f / (dr * dr + di * di);
        for (int p = pmin; p < 7; ++p) {
            int ii = i - p;
            if (ii < 0 || ii > 10) continue;
            float ap = blur[p * 7 + 3];
            float nr = pr[ii * 11 + 5], ni = pi[ii * 11 + 5];
            float f = comp ? (ni * dr - nr * di) * inv
                           : (nr * dr + ni * di) * inv;
            val += ap * f;
        }
    }
    fhp[g] = val;
}

// ---------------- k_fused5: one block per (Y, src2, n), 512 thr ------------
__global__ __launch_bounds__(512, 6) void k_fused5(const float* __restrict__ img,
                                                   const float* __restrict__ psi_re,
                                                   const float* __restrict__ psi_im,
                                                   const float* __restrict__ blur,
                                                   const float* __restrict__ fhp,
                                                   float* __restrict__ out) {
    __shared__ __align__(16) float bufA[7452];   // fp32 strip [27][276] / packed s1 [17][298]
    __shared__ __align__(16) float bufB[5100];   // packed Iv [17][300] / C fp32 6*600
    unsigned* s1P = (unsigned*)bufA;
    unsigned* ivP = (unsigned*)bufB;
    const int tid = threadIdx.x;
    const int lane = tid & 63;
    const int wave = tid >> 6;
    const int Y = blockIdx.x;
    const int src2 = blockIdx.y;    // 0 img, 1 g0, 2 g5, 3..6 pairs
    const int n = blockIdx.z;
    size_t nb = (size_t)n * 111 * 1024;
    const float* im = img + n * 65536;

    const bool isimg = (src2 == 0);
    const bool paired = (src2 >= 3);
    int ga = 0, gb = 0;
    if (src2 == 1) ga = gb = 0;
    else if (src2 == 2) ga = gb = 5;
    else if (paired) {
        int p2 = src2 - 3;
        ga = (p2 < 2) ? 1 + p2 : 4 + p2;      // 1,2,6,7
        gb = (p2 < 2) ? 4 - p2 : 11 - p2;     // 4,3,9,8
    }

    if (isimg) {
        // stage img strip [17 rows] packed (v,v) into W1 layout, direct from
        // img with predicates (strip col cc = 4c4+e <-> img col cc-8; row
        // gr = 8Y-8+r). cols cc>264 zeroed (alias row r+1 t0..6 slots).
        int rb = 8 * Y - 8;
        for (int idx = tid; idx < 17 * 68; idx += 512) {
            int r = idx / 68, c4 = idx - r * 68;
            int gr = rb + r;
            float4 v = {0.f, 0.f, 0.f, 0.f};
            if (gr >= 0 && gr < 256 && c4 >= 2 && c4 <= 65)
                v = *(const float4*)(im + gr * 256 + 4 * c4 - 8);
            int c = 4 * c4;
            int d = r * W1 + c + (c >> 3);   // (c>>3) constant within a float4
            float vs[4] = {v.x, v.y, v.z, v.w};
#pragma unroll
            for (int e = 0; e < 4; ++e) {
                float val = (c + e > 264) ? 0.f : vs[e];
                s1P[d + e] = packbf2(val, val);
            }
        }
    } else {
        const float* pr = psi_re + ga * 121;   // block-uniform -> s_load
        const float* pi = psi_im + ga * 121;
        float dr = pr[60], di = pi[60];
        float inv = rsqrtf(dr * dr + di * di);

        // stage fp32 strip [27][276]: img rows 8Y-13.., strip col cc = img+8
        int rb2 = 8 * Y - 13;
        for (int idx = tid; idx < 27 * 68; idx += 512) {
            int r = idx / 68, c4 = idx - r * 68;
            int gr = rb2 + r;
            float4 v = {0.f, 0.f, 0.f, 0.f};
            if (gr >= 0 && gr < 256 && c4 >= 2 && c4 <= 65)
                v = *(const float4*)(im + gr * 256 + 4 * c4 - 8);
            *(float4*)(bufA + r * SSTR + 4 * c4) = v;
        }
        __syncthreads();

        // Iv packed (re|im): lane = col v, 8 rows/task (conflict-free reads)
        for (int task = tid; task < 532; task += 512) {
            int rg = (task >= 266) ? 1 : 0;
            int v = task - rg * 266;
            int r0 = rg * 8;
            const float* sp = bufA + r0 * SSTR + v + 3;
            float xv[18];
#pragma unroll
            for (int p = 0; p < 18; ++p) xv[p] = sp[p * SSTR];
            int dsw = v + (v >> 3);
            unsigned* dP = ivP + r0 * IVSTR + dsw;
#pragma unroll
            for (int m = 0; m < 8; ++m) {
                float ar = 0.f, ai = 0.f;
#pragma unroll
                for (int p = 0; p < 11; ++p) {
                    ar = fmaf(pr[p * 11 + 5], xv[m + p], ar);
                    ai = fmaf(pi[p * 11 + 5], xv[m + p], ai);
                }
                dP[m * IVSTR] = packbf2(ar, ai);
            }
        }
        if (tid < 266) {                     // row 16
            int v = tid;
            const float* sp = bufA + 16 * SSTR + v + 3;
            float ar = 0.f, ai = 0.f;
#pragma unroll
            for (int p = 0; p < 11; ++p) {
                float x = sp[p * SSTR];
                ar = fmaf(pr[p * 11 + 5], x, ar);
                ai = fmaf(pi[p * 11 + 5], x, ai);
            }
            ivP[16 * IVSTR + v + (v >> 3)] = packbf2(ar, ai);
        }
        __syncthreads();

        // s1 packed (chanA|chanB): 18 packed reads -> 36 values
        int rowbase = 8 * Y - 8;
        for (int t2 = tid; t2 < 544; t2 += 512) {
            int r = t2 >> 5, xg = t2 & 31;
            int ry = rowbase + r;
            int wb = r * W1 + 9 * xg + 9;
            if (ry >= 0 && ry < 256) {
                const unsigned* sP = ivP + r * IVSTR + 9 * xg;
                float xr[18], xi[18];
#pragma unroll
                for (int j = 0; j < 18; ++j) {
                    unsigned u = sP[j + (j >> 3)];
                    xr[j] = unplo(u);
                    xi[j] = unphi(u);
                }
                if (paired) {
#pragma unroll
                    for (int m = 0; m < 8; ++m) {
                        float a = 0.f, b = 0.f, c = 0.f, d = 0.f;
#pragma unroll
                        for (int j = 0; j < 11; ++j) {
                            float hr = pr[55 + j], hi2 = pi[55 + j];
                            a = fmaf(hr, xr[m + j], a);
                            b = fmaf(hi2, xi[m + j], b);
                            c = fmaf(hr, xi[m + j], c);
                            d = fmaf(hi2, xr[m + j], d);
                        }
                        float e1 = a - b, o1 = c + d;
                        float e2 = a + b, o2 = c - d;
                        s1P[wb + m] = packbf2(inv * sqrtf(fmaf(e1, e1, o1 * o1)),
                                              inv * sqrtf(fmaf(e2, e2, o2 * o2)));
                    }
                } else {
#pragma unroll
                    for (int m = 0; m < 8; ++m) {
                        float sr = 0.f, si = 0.f;
#pragma unroll
                        for (int j = 0; j < 11; ++j) {
                            float hr = pr[55 + j], hi2 = pi[55 + j];
                            sr = fmaf(hr, xr[m + j], fmaf(-hi2, xi[m + j], sr));
                            si = fmaf(hr, xi[m + j], fmaf(hi2, xr[m + j], si));
                        }
                        float val = inv * sqrtf(fmaf(sr, sr, si * si));
                        s1P[wb + m] = packbf2(val, val);
                    }
                }
            } else {
#pragma unroll
                for (int m = 0; m < 8; ++m) s1P[wb + m] = 0u;
            }
        }
        if (tid < 17) {                      // edge zeros: t 0..7 and t 264 slot
            int r = tid;
#pragma unroll
            for (int t = 0; t < 8; ++t) s1P[r * W1 + t] = 0u;
            s1P[r * W1 + 297] = 0u;
        }
    }
    __syncthreads();

    // ---- per-source: C (6 planes fp32, overwrites Iv) then out ----
    const int nsrc = paired ? 2 : 1;
    for (int sh = 0; sh < nsrc; ++sh) {
        {
            int kh = __builtin_amdgcn_readfirstlane(wave >> 2);   // plane half
            int wl = wave & 3;
            int fro = (Y == 0) ? 102 : 68;
            int fio = (Y == 0) ? 119 : 85;
            {   // main pass: t 0..255
                int t = (wl << 6) + lane;
                int tsw = t + (t >> 3);
                float v[17];
#pragma unroll
                for (int i = 0; i < 17; ++i) {
                    unsigned u = s1P[i * W1 + tsw];
                    v[i] = sh ? unphi(u) : unplo(u);
                }
                for (int kk = 0; kk < 3; ++kk) {      // <=34 weights live
                    int k = kh * 5 + kk;              // {0,1,2} / {5,6,7}
                    int p = kh * 3 + kk;
                    const float* fR = fhp + k * 136 + fro;   // uniform -> s_load
                    const float* fI = fhp + k * 136 + fio;
                    float cr = 0.f, ci = 0.f;
#pragma unroll
                    for (int i = 0; i < 17; ++i) {
                        cr = fmaf(fR[i], v[i], cr);
                        ci = fmaf(fI[i], v[i], ci);
                    }
                    bufB[p * CSTR + tsw] = cr;
                    bufB[p * CSTR + 300 + tsw] = ci;
                }
            }
            int wv = __builtin_amdgcn_readfirstlane(wave);
            if (wv < 6 && lane < 9) {                 // balanced tail t 256..264
                int t = 256 + lane;
                int tsw = t + (t >> 3);
                float v[17];
#pragma unroll
                for (int i = 0; i < 17; ++i) {
                    unsigned u = s1P[i * W1 + tsw];
                    v[i] = sh ? unphi(u) : unplo(u);
                }
                int k = (wv < 3) ? wv : wv + 2;
                const float* fR = fhp + k * 136 + fro;
                const float* fI = fhp + k * 136 + fio;
                float cr = 0.f, ci = 0.f;
#pragma unroll
                for (int i = 0; i < 17; ++i) {
                    cr = fmaf(fR[i], v[i], cr);
                    ci = fmaf(fI[i], v[i], ci);
                }
                bufB[wv * CSTR + tsw] = cr;
                bufB[wv * CSTR + 300 + tsw] = ci;
            }
        }
        __syncthreads();

        if (tid < 192) {          // out: 6 plane-sets x 32 X, partners via u±v
            int s = tid >> 5, X = tid & 31;
            int kdist = (s < 3) ? s : s + 2;          // {0,1,2,5,6,7}
            const float* hb = fhp + kdist * 136 + ((X == 0) ? 34 : 0);
            const float* cR = bufB + s * CSTR + 9 * X;
            float u = 0.f, v2 = 0.f;
#pragma unroll
            for (int j = 0; j < 17; ++j) {
                int off = j + (j >> 3);
                u  = fmaf(hb[j], cR[off], u);
                v2 = fmaf(hb[17 + j], cR[off + 300], v2);
            }
            int g = sh ? gb : ga;
            int ch0 = isimg ? 1 : 11 + g * 10;
            out[nb + (size_t)(ch0 + kdist) * 1024 + Y * 32 + X] = u - v2;
            if (s == 1 || s == 2 || s == 4 || s == 5) {
                int partner = (s < 3) ? 5 - s : 13 - s;   // 4,3,9,8
                out[nb + (size_t)(ch0 + partner) * 1024 + Y * 32 + X] = u + v2;
            }
        } else if (isimg && tid < 224) {              // s0: clipped 7x7 blur
            int X = tid - 192;
            float s0 = 0.f;
#pragma unroll
            for (int p = 0; p < 7; ++p)
#pragma unroll
                for (int q = 0; q < 7; ++q) {
                    int c = 8 * X + q + 5;
                    s0 = fmaf(blur[p * 7 + q],
                              unplo(s1P[(p + 5) * W1 + c + (c >> 3)]), s0);
                }
            out[nb + Y * 32 + X] = s0;
        }
        if (sh + 1 < nsrc) __syncthreads();
    }
}

extern "C" void kernel_launch(void* const* d_in, const int* in_sizes, int n_in,
                              void* d_out, int out_size, void* d_ws, size_t ws_size,
                              hipStream_t stream) {
    const float* img    = (const float*)d_in[0];
    const float* psi_re = (const float*)d_in[1];
    const float* psi_im = (const float*)d_in[2];
    const float* blur   = (const float*)d_in[3];
    float* out = (float*)d_out;
    float* fhp = (float*)d_ws;

    k_fhp<<<22, 64, 0, stream>>>(psi_re, psi_im, blur, fhp);

    dim3 g2(32, 7, 8);
    k_fused5<<<g2, 512, 0, stream>>>(img, psi_re, psi_im, blur, fhp, out);
}